// Round 7
// baseline (287.864 us; speedup 1.0000x reference)
//
#include <hip/hip_runtime.h>

// Bilinear warp (grid_sample align_corners=True, padding_mode='border').
// src: [B=8, C=16, H=512, W=512] f32, flow: [B, 2, H, W] f32 -> out [B,C,H,W] f32.
//
// R1: XCD-chunked swizzle (kept). R2: float2 tap-pair gathers (kept).
// R5: LDS staging regressed (occupancy+bank conflicts). Reverted.
// R6 post-mortem: latency/MLP theory FALSIFIED (in-flight demand >> BW*lat;
//   VGPR pinned at 40 regardless of launch_bounds). The quantity invariant
//   across all flat rounds is DISTINCT L1 LINES per gather footprint
//   (64x1-pixel waves -> ~35 lines/channel/wave, ~70K line-fills per CU;
//   at ~200cy L2 latency and bounded L1 miss queue -> ~1 fill/5cy -> ~120us,
//   matching all measurements).
// R7: wave geometry 64x1 -> 4x16 (block = 16x16 pixel tile). Per-channel wave
//   gather footprint: (4+5) rows x 2-3 lines = ~13-18 distinct lines vs 35.
//   Stores stay perfectly coalesced: w0 = tx*16 -> 64B-aligned, each store
//   wave-instr = 4 exactly-packed lines. Swizzle chunk = 1024 blocks = one
//   image per XCD, so all tile-neighbor reuse stays in one L2.

#define BB 8
#define CC 16
#define HH 512
#define WW 512

// 8-byte vector with declared 4-byte alignment so the compiler may emit a
// single global_load_dwordx2 at any dword-aligned address.
typedef float f2u __attribute__((ext_vector_type(2), aligned(4)));

__global__ __launch_bounds__(256) void warp_kernel(
    const float* __restrict__ src,
    const float* __restrict__ flow,
    float* __restrict__ out)
{
    const int HW = HH * WW;              // 262144
    const int NWG = (BB * HW) / 256;     // 8192 workgroups, divisible by 8
    const int CHUNK = NWG / 8;           // 1024 per XCD = exactly one image

    // bijective XCD-chunked swizzle: XCD k gets blocks [k*CHUNK, (k+1)*CHUNK)
    int bid = (int)blockIdx.x;
    int swz = (bid & 7) * CHUNK + (bid >> 3);

    // 16x16 pixel tile per block; wave = 4 rows x 16 cols.
    int b   = swz >> 10;                 // image
    int til = swz & 1023;                // tile in image (32x32 tiles)
    int ty  = til >> 5;
    int tx  = til & 31;
    int t   = (int)threadIdx.x;
    int h   = (ty << 4) + (t >> 4);
    int w   = (tx << 4) + (t & 15);
    int hw  = (h << 9) + w;

    const float* fb = flow + (size_t)b * 2 * HW;
    float f0 = __builtin_nontemporal_load(fb + hw);        // y displacement
    float f1 = __builtin_nontemporal_load(fb + HW + hw);   // x displacement

    float py = fminf(fmaxf((float)h + f0, 0.0f), (float)(HH - 1));
    float px = fminf(fmaxf((float)w + f1, 0.0f), (float)(WW - 1));

    // Border-exact reformulation: clamp the low corner to H-2/W-2 and let the
    // fractional weight reach 1. At py=511: yl=510, wy=1 -> full weight on
    // row 511 (identical result). No per-tap clamps needed.
    int yl = min((int)py, HH - 2);       // py >= 0, so (int) == floor
    int xl = min((int)px, WW - 2);
    float wy = py - (float)yl;
    float wx = px - (float)xl;

    float w00 = (1.0f - wy) * (1.0f - wx);
    float w01 = (1.0f - wy) * wx;
    float w10 = wy * (1.0f - wx);
    float w11 = wy * wx;

    int u0 = (yl << 9) + xl;             // low row, cols [xl, xl+1]
    int u1 = u0 + WW;                    // high row (yl+1 <= 511)

    const float* sb = src + (size_t)b * CC * HW;
    float*       ob = out + (size_t)b * CC * HW;

    // Issue both tap-pair gathers per channel; consume oldest-first.
    f2u r0[CC], r1[CC];
    #pragma unroll
    for (int c = 0; c < CC; ++c) {
        const float* sc = sb + c * HW;
        r0[c] = *reinterpret_cast<const f2u*>(sc + u0);   // {v00, v01}
        r1[c] = *reinterpret_cast<const f2u*>(sc + u1);   // {v10, v11}
    }
    __builtin_amdgcn_sched_barrier(0);

    #pragma unroll
    for (int c = 0; c < CC; ++c) {
        float v = r0[c].x * w00 + r0[c].y * w01
                + r1[c].x * w10 + r1[c].y * w11;
        __builtin_nontemporal_store(v, ob + c * HW + hw);
    }
}

extern "C" void kernel_launch(void* const* d_in, const int* in_sizes, int n_in,
                              void* d_out, int out_size, void* d_ws, size_t ws_size,
                              hipStream_t stream) {
    const float* src  = (const float*)d_in[0];
    const float* flow = (const float*)d_in[1];
    float* out = (float*)d_out;

    const int n_pix = BB * HH * WW;          // 2,097,152
    dim3 block(256);
    dim3 grid(n_pix / 256);                  // 8192 blocks (exact)
    warp_kernel<<<grid, block, 0, stream>>>(src, flow, out);
}

// Round 10
// 267.648 us; speedup vs baseline: 1.0755x; 1.0755x over previous
//
#include <hip/hip_runtime.h>

// Bilinear warp (grid_sample align_corners=True, padding_mode='border').
// src: [B=8, C=16, H=512, W=512] f32, flow: [B, 2, H, W] f32 -> out [B,C,H,W] f32.
//
// R7 post-mortem: TCP transactions per tap (~0.6) are invariant to wave
// geometry — jitter +-3px makes 64 lanes hit ~35-40 distinct 64B lines for
// ANY footprint shape. Only densification fixes it: stage the window
// coalesced (64 floats/line useful) and do the divergent read in LDS.
// R8 = R5's idea minus R5's failures:
//   - tile 8x32 (1px/thread): stores are two FULL 128B lines per wave instr
//     (R7's write regression fixed), window 16 rows x 64 cols = 4KB/channel.
//   - LDS 8.7KB double-buffer (stride 68 words), VGPR ~48 -> occupancy OK
//     (R5: 33KB + VGPR136 -> 11%).
//   - staging = exactly 1 float4/thread/channel, issued one channel ahead;
//     ds_write after compute; ONE barrier per channel (R5: serialized 8-load
//     batches + 2 barriers).
//   - per-pixel window-validity check with global-gather fallback (correct
//     for arbitrary flow; ~never taken for N(0,1)).
//   (R8/R9 benches were infra failures — container died twice each; the
//    identical-source R3->R4 precedent says resubmit unchanged.)

#define BB 8
#define CC 16
#define HH 512
#define WW 512
#define HW (HH*WW)

#define NR   16     // staged rows per window
#define NCOL 64     // staged cols per window (16-float aligned base)
#define LST  68     // LDS row stride in words (64 + 4 pad -> 4-bank row shift)

typedef float f2u __attribute__((ext_vector_type(2), aligned(4)));
typedef float f4u __attribute__((ext_vector_type(4), aligned(16)));

__global__ __launch_bounds__(256) void warp_kernel(
    const float* __restrict__ src,
    const float* __restrict__ flow,
    float* __restrict__ out)
{
    __shared__ float tile[2][NR * LST];   // 8704 B
    __shared__ int red[4];

    // XCD-chunked swizzle: 8192 blocks, 1024 per XCD = exactly one image.
    int bid = (int)blockIdx.x;
    int swz = (bid & 7) * 1024 + (bid >> 3);
    int b   = swz >> 10;                 // image
    int til = swz & 1023;                // 64 row-tiles x 16 col-tiles
    int hb  = (til >> 4) << 3;           // 8 rows per tile
    int wb  = (til & 15) << 5;           // 32 cols per tile
    int t   = (int)threadIdx.x;
    int h   = hb + (t >> 5);
    int w   = wb + (t & 31);
    int hw  = (h << 9) + w;

    const float* fb = flow + (size_t)b * 2 * HW;
    float f0 = __builtin_nontemporal_load(fb + hw);        // y displacement
    float f1 = __builtin_nontemporal_load(fb + HW + hw);   // x displacement

    float py = fminf(fmaxf((float)h + f0, 0.0f), (float)(HH - 1));
    float px = fminf(fmaxf((float)w + f1, 0.0f), (float)(WW - 1));

    // Border-exact: clamp low corner to H-2/W-2 and let the weight reach 1.
    int yl = min((int)py, HH - 2);
    int xl = min((int)px, WW - 2);
    float wy = py - (float)yl, wx = px - (float)xl;
    float w00 = (1.0f - wy) * (1.0f - wx);
    float w01 = (1.0f - wy) * wx;
    float w10 = wy * (1.0f - wx);
    float w11 = wy * wx;

    // Block-min of yl -> dynamic row window start.
    int mn = yl;
    #pragma unroll
    for (int off = 32; off; off >>= 1) mn = min(mn, __shfl_xor(mn, off));
    if ((t & 63) == 0) red[t >> 6] = mn;
    __syncthreads();
    int ys = min(min(min(red[0], red[1]), min(red[2], red[3])), HH - NR);

    int cs = min(max(wb - 16, 0), WW - NCOL);     // 16-float aligned
    int loff  = (yl - ys) * LST + (xl - cs);
    bool valid = ((yl - ys) <= NR - 2) & ((unsigned)(xl - cs) <= NCOL - 2);
    int u0 = (yl << 9) + xl;                      // global fallback offset

    // Staging role: thread t loads one float4 at (row t>>4, colgroup t&15).
    int rr  = t >> 4, ck = (t & 15) << 2;
    int lso = rr * LST + ck;
    const float* sst = src + (size_t)b * CC * HW + (size_t)(ys + rr) * WW + cs + ck;
    const float* sg  = src + (size_t)b * CC * HW;
    float*       ob  = out + (size_t)b * CC * HW + hw;

    // Prologue: stage channel 0.
    *reinterpret_cast<f4u*>(&tile[0][lso]) = *reinterpret_cast<const f4u*>(sst);
    __syncthreads();

    for (int c = 0; c < CC; ++c) {
        // Issue next channel's staging load early — hides under this
        // channel's LDS compute + store.
        f4u nx;
        if (c + 1 < CC) nx = *reinterpret_cast<const f4u*>(sst + (size_t)(c + 1) * HW);

        const float* tl = tile[c & 1];
        float v;
        if (valid) {
            f2u a = *reinterpret_cast<const f2u*>(&tl[loff]);
            f2u d = *reinterpret_cast<const f2u*>(&tl[loff + LST]);
            v = a.x * w00 + a.y * w01 + d.x * w10 + d.y * w11;
        } else {
            // Rare window-overflow fallback: direct global tap-pair gather.
            const float* s = sg + (size_t)c * HW;
            f2u a = *reinterpret_cast<const f2u*>(s + u0);
            f2u d = *reinterpret_cast<const f2u*>(s + u0 + WW);
            v = a.x * w00 + a.y * w01 + d.x * w10 + d.y * w11;
        }
        __builtin_nontemporal_store(v, ob + (size_t)c * HW);

        if (c + 1 < CC) {
            // buf[(c+1)&1] was last read in iter c-1, separated by that
            // iter's barrier -> safe to overwrite without a second barrier.
            *reinterpret_cast<f4u*>(&tile[(c + 1) & 1][lso]) = nx;
            __syncthreads();
        }
    }
}

extern "C" void kernel_launch(void* const* d_in, const int* in_sizes, int n_in,
                              void* d_out, int out_size, void* d_ws, size_t ws_size,
                              hipStream_t stream) {
    const float* src  = (const float*)d_in[0];
    const float* flow = (const float*)d_in[1];
    float* out = (float*)d_out;

    dim3 block(256);
    dim3 grid(8192);                 // 8 images x 1024 (8x32) tiles
    warp_kernel<<<grid, block, 0, stream>>>(src, flow, out);
}